// Round 4
// baseline (621.202 us; speedup 1.0000x reference)
//
#include <hip/hip_runtime.h>
#include <math.h>

#define NUM_CLASSES 80
#define MT 50              // max targets per image
#define ATOT 8400          // 80*80 + 40*40 + 20*20
#define CH 85              // 5 + NUM_CLASSES
#define EPI (ATOT * CH)    // 714000 floats per image
#define BLOCK 256
#define NBY 33             // ceil(ATOT / BLOCK)
#define BPI 698            // ceil(EPI / (BLOCK*4))

__device__ __forceinline__ float softplus_fast(float x) {
    // stable softplus via HW transcendentals: max(x,0) + log(1 + exp(-|x|))
    return fmaxf(x, 0.0f) + __logf(1.0f + __expf(-fabsf(x)));
}

__global__ void zero_acc_kernel(float* acc, int n) {
    int i = blockIdx.x * blockDim.x + threadIdx.x;
    if (i < n) acc[i] = 0.0f;
}

// ---------------- Kernel A: anchor->target match, box IoU, pos mask --------
__global__ __launch_bounds__(BLOCK) void yolox_match(
        const float* __restrict__ pred,   // [B, ATOT, CH]
        const float* __restrict__ tgt,    // [B, MT, 5]
        const int*   __restrict__ isz,
        int*   __restrict__ mask,         // [B, ATOT]  pos ? gcls : -1
        float* __restrict__ acc) {        // [B, 4] obj, cls, box, np
    const int b = blockIdx.y;
    const int a = blockIdx.x * BLOCK + threadIdx.x;

    __shared__ float  raw[MT * 5];
    __shared__ float2 sxy[MT];
    __shared__ float2 swh[MT];
    __shared__ float  scls[MT];
    __shared__ int    snv;

    for (int i = threadIdx.x; i < MT * 5; i += BLOCK)
        raw[i] = tgt[(size_t)b * MT * 5 + i];
    __syncthreads();
    if (threadIdx.x == 0) {
        const float fsize = (float)(*isz);
        int nv = 0;
        for (int m = 0; m < MT; ++m) {
            const float c = raw[m * 5 + 0];
            if (c >= 0.0f) {
                sxy[nv]  = make_float2(raw[m * 5 + 1] * fsize, raw[m * 5 + 2] * fsize);
                swh[nv]  = make_float2(raw[m * 5 + 3] * fsize, raw[m * 5 + 4] * fsize);
                scls[nv] = c;
                ++nv;
            }
        }
        snv = nv;
    }
    __syncthreads();
    const int nv = snv;

    float box_sum = 0.f, pos_cnt = 0.f;

    if (a < ATOT) {
        int s, n, idx;
        if (a < 6400)      { s = 8;  n = 80; idx = a; }
        else if (a < 8000) { s = 16; n = 40; idx = a - 6400; }
        else               { s = 32; n = 20; idx = a - 8000; }
        const int yy = idx / n;
        const int xx = idx - yy * n;
        const float ax = (float)(xx * s + (s >> 1));
        const float ay = (float)(yy * s + (s >> 1));

        float best = INFINITY;
        int bestm = 0;
        for (int m = 0; m < nv; ++m) {
            const float2 g = sxy[m];
            const float dx = g.x - ax, dy = g.y - ay;
            const float d2 = dx * dx + dy * dy;
            if (d2 < best) { best = d2; bestm = m; }
        }
        const bool pos = best < 4096.0f;  // 64^2

        mask[(size_t)b * ATOT + a] = pos ? (int)scls[bestm] : -1;

        if (pos) {
            pos_cnt = 1.0f;
            const float* p = pred + ((size_t)b * ATOT + (size_t)a) * CH;
            const float pcx = p[0], pcy = p[1];
            const float pw = __expf(p[2]), ph = __expf(p[3]);
            const float2 g  = sxy[bestm];
            const float2 wh = swh[bestm];
            const float p1x = pcx - pw * 0.5f, p2x = pcx + pw * 0.5f;
            const float p1y = pcy - ph * 0.5f, p2y = pcy + ph * 0.5f;
            const float t1x = g.x - wh.x * 0.5f, t2x = g.x + wh.x * 0.5f;
            const float t1y = g.y - wh.y * 0.5f, t2y = g.y + wh.y * 0.5f;
            const float iw = fminf(p2x, t2x) - fmaxf(p1x, t1x);
            const float ih = fminf(p2y, t2y) - fmaxf(p1y, t1y);
            const float inter = fmaxf(iw, 0.f) * fmaxf(ih, 0.f);
            const float pa = (p2x - p1x) * (p2y - p1y);
            const float ta = (t2x - t1x) * (t2y - t1y);
            const float uni = pa + ta - inter;
            box_sum = 1.0f - inter / (uni + 1e-6f);
        }
    }

    // block reduce box_sum, pos_cnt
    float v2 = box_sum, v3 = pos_cnt;
    for (int off = 32; off > 0; off >>= 1) {
        v2 += __shfl_down(v2, off, 64);
        v3 += __shfl_down(v3, off, 64);
    }
    __shared__ float sred[BLOCK / 64][2];
    const int wave = threadIdx.x >> 6;
    const int lane = threadIdx.x & 63;
    if (lane == 0) { sred[wave][0] = v2; sred[wave][1] = v3; }
    __syncthreads();
    if (threadIdx.x == 0) {
        float t2 = 0.f, t3 = 0.f;
        #pragma unroll
        for (int w = 0; w < BLOCK / 64; ++w) { t2 += sred[w][0]; t3 += sred[w][1]; }
        atomicAdd(&acc[b * 4 + 2], t2);
        atomicAdd(&acc[b * 4 + 3], t3);
    }
}

// ---------------- Kernel B: coalesced bulk obj/cls BCE sweep ----------------
__global__ __launch_bounds__(BLOCK) void yolox_bulk(
        const float* __restrict__ pred,   // [B, ATOT, CH]
        const int*   __restrict__ mask,   // [B, ATOT]
        float* __restrict__ acc) {        // [B, 4]
    const int b = blockIdx.y;
    const int e0 = (blockIdx.x * BLOCK + threadIdx.x) * 4;

    float obj_s = 0.f, cls_s = 0.f;

    if (e0 < EPI) {
        // a0 = e0 / 85 via magic mul (valid for e0 < 2^32/ample margin)
        const unsigned a0 = __umulhi((unsigned)e0, 3233857729u) >> 6;
        const int c0 = e0 - (int)a0 * CH;
        const int m0 = mask[(size_t)b * ATOT + a0];

        // contributions only come from elements of anchor a0:
        //   c==4 (obj, all anchors)  -> requires c0 in [1,4]
        //   c>=5 with pos anchor     -> requires m0>=0 and c0>=2
        // wrapped elements (next anchor, c in [0,2]) never contribute.
        const bool need = (c0 >= 1 && c0 <= 4) || (m0 >= 0 && c0 >= 2);
        if (need) {
            const float4 x4 = *(const float4*)(pred + (size_t)b * EPI + e0);
            const float xs[4] = {x4.x, x4.y, x4.z, x4.w};
            #pragma unroll
            for (int j = 0; j < 4; ++j) {
                const int c = c0 + j;
                if (c == 4) {
                    obj_s += softplus_fast(xs[j]) - (m0 >= 0 ? xs[j] : 0.0f);
                } else if (c >= 5 && c < CH && m0 >= 0) {
                    cls_s += softplus_fast(xs[j]);
                    if (c - 5 == m0) cls_s -= xs[j];
                }
            }
        }
    }

    // block reduce obj_s, cls_s
    float v0 = obj_s, v1 = cls_s;
    for (int off = 32; off > 0; off >>= 1) {
        v0 += __shfl_down(v0, off, 64);
        v1 += __shfl_down(v1, off, 64);
    }
    __shared__ float sred[BLOCK / 64][2];
    const int wave = threadIdx.x >> 6;
    const int lane = threadIdx.x & 63;
    if (lane == 0) { sred[wave][0] = v0; sred[wave][1] = v1; }
    __syncthreads();
    if (threadIdx.x == 0) {
        float t0 = 0.f, t1 = 0.f;
        #pragma unroll
        for (int w = 0; w < BLOCK / 64; ++w) { t0 += sred[w][0]; t1 += sred[w][1]; }
        atomicAdd(&acc[b * 4 + 0], t0);
        atomicAdd(&acc[b * 4 + 1], t1);
    }
}

// ---------------- Stage 2: per-image normalize + final reduce ---------------
__global__ void yolox_stage2(const float* __restrict__ acc,
                             float* __restrict__ out, int B) {
    float obj = 0.f, cls = 0.f, box = 0.f, np = 0.f;
    for (int b = threadIdx.x; b < B; b += 64) {
        const float os = acc[b * 4 + 0];
        const float cs = acc[b * 4 + 1];
        const float bs = acc[b * 4 + 2];
        const float ps = acc[b * 4 + 3];
        obj += os * (1.0f / (float)ATOT);
        const float denom = fmaxf(ps, 1.0f);
        cls += (ps > 0.f) ? cs / (denom * (float)NUM_CLASSES) : 0.f;
        box += (ps > 0.f) ? bs / denom : 0.f;
        np  += ps;
    }
    for (int off = 32; off > 0; off >>= 1) {
        obj += __shfl_down(obj, off, 64);
        cls += __shfl_down(cls, off, 64);
        box += __shfl_down(box, off, 64);
        np  += __shfl_down(np,  off, 64);
    }
    if (threadIdx.x == 0) {
        out[0] = 5.0f * box + obj + cls;  // total
        out[1] = box;
        out[2] = obj;
        out[3] = cls;
        out[4] = np;
    }
}

extern "C" void kernel_launch(void* const* d_in, const int* in_sizes, int n_in,
                              void* d_out, int out_size, void* d_ws, size_t ws_size,
                              hipStream_t stream) {
    const float* pred = (const float*)d_in[0];
    const float* tgt  = (const float*)d_in[1];
    const int*   isz  = (const int*)d_in[2];
    float* out = (float*)d_out;

    const int B = in_sizes[1] / (MT * 5);

    float* acc  = (float*)d_ws;                 // B*4 floats
    int*   mask = (int*)((char*)d_ws + ((size_t)B * 4 * sizeof(float) + 255) / 256 * 256);

    zero_acc_kernel<<<1, BLOCK, 0, stream>>>(acc, B * 4);

    dim3 gridA(NBY, B);
    yolox_match<<<gridA, BLOCK, 0, stream>>>(pred, tgt, isz, mask, acc);

    dim3 gridB(BPI, B);
    yolox_bulk<<<gridB, BLOCK, 0, stream>>>(pred, mask, acc);

    yolox_stage2<<<1, 64, 0, stream>>>(acc, out, B);
}

// Round 5
// 285.285 us; speedup vs baseline: 2.1775x; 2.1775x over previous
//
#include <hip/hip_runtime.h>
#include <math.h>

#define NUM_CLASSES 80
#define MT 50              // max targets per image
#define ATOT 8400          // 80*80 + 40*40 + 20*20
#define CH 85              // 5 + NUM_CLASSES
#define BLOCK 256
#define CHUNK 256          // anchors per block
#define NBY 33             // ceil(ATOT / CHUNK)

__device__ __forceinline__ float softplus_fast(float x) {
    // stable softplus via HW transcendentals: max(x,0) + log(1 + exp(-|x|))
    return fmaxf(x, 0.0f) + __logf(1.0f + __expf(-fabsf(x)));
}

__global__ void zero_acc_kernel(float* acc, int n) {
    int i = blockIdx.x * blockDim.x + threadIdx.x;
    if (i < n) acc[i] = 0.0f;
}

// One block = (image b, 256-anchor chunk). Phase 1: match + box IoU, mask in
// LDS. Phase 2: coalesced float4 sweep of the chunk's contiguous pred slice.
__global__ __launch_bounds__(BLOCK) void yolox_fused(
        const float* __restrict__ pred,   // [B, ATOT, CH]
        const float* __restrict__ tgt,    // [B, MT, 5]
        const int*   __restrict__ isz,
        float* __restrict__ acc) {        // [B, 4] obj, cls, box, np
    const int b  = blockIdx.y;
    const int by = blockIdx.x;
    const int a0 = by * CHUNK;
    const int nanch = min(CHUNK, ATOT - a0);

    __shared__ float  raw[MT * 5];
    __shared__ float2 sxy[MT];
    __shared__ float2 swh[MT];
    __shared__ float  scls[MT];
    __shared__ int    snv;
    __shared__ int    smask[CHUNK];   // pos ? gcls : -1

    for (int i = threadIdx.x; i < MT * 5; i += BLOCK)
        raw[i] = tgt[(size_t)b * MT * 5 + i];
    __syncthreads();
    if (threadIdx.x == 0) {
        const float fsize = (float)(*isz);
        int nv = 0;
        for (int m = 0; m < MT; ++m) {
            const float c = raw[m * 5 + 0];
            if (c >= 0.0f) {
                sxy[nv]  = make_float2(raw[m * 5 + 1] * fsize, raw[m * 5 + 2] * fsize);
                swh[nv]  = make_float2(raw[m * 5 + 3] * fsize, raw[m * 5 + 4] * fsize);
                scls[nv] = c;
                ++nv;
            }
        }
        snv = nv;
    }
    __syncthreads();
    const int nv = snv;

    // ---------------- Phase 1: match + box IoU ----------------
    float box_s = 0.f, np_s = 0.f;
    smask[threadIdx.x] = -1;

    const int a = a0 + threadIdx.x;
    if (threadIdx.x < nanch) {
        int s, n, idx;
        if (a < 6400)      { s = 8;  n = 80; idx = a; }
        else if (a < 8000) { s = 16; n = 40; idx = a - 6400; }
        else               { s = 32; n = 20; idx = a - 8000; }
        const int yy = idx / n;
        const int xx = idx - yy * n;
        const float ax = (float)(xx * s + (s >> 1));
        const float ay = (float)(yy * s + (s >> 1));

        float best = INFINITY;
        int bestm = 0;
        for (int m = 0; m < nv; ++m) {
            const float2 g = sxy[m];
            const float dx = g.x - ax, dy = g.y - ay;
            const float d2 = dx * dx + dy * dy;
            if (d2 < best) { best = d2; bestm = m; }
        }
        const bool pos = best < 4096.0f;  // 64^2

        if (pos) {
            smask[threadIdx.x] = (int)scls[bestm];
            np_s = 1.0f;
            const float* p = pred + ((size_t)b * ATOT + (size_t)a) * CH;
            const float pcx = p[0], pcy = p[1];
            const float pw = __expf(p[2]), ph = __expf(p[3]);
            const float2 g  = sxy[bestm];
            const float2 wh = swh[bestm];
            const float p1x = pcx - pw * 0.5f, p2x = pcx + pw * 0.5f;
            const float p1y = pcy - ph * 0.5f, p2y = pcy + ph * 0.5f;
            const float t1x = g.x - wh.x * 0.5f, t2x = g.x + wh.x * 0.5f;
            const float t1y = g.y - wh.y * 0.5f, t2y = g.y + wh.y * 0.5f;
            const float iw = fminf(p2x, t2x) - fmaxf(p1x, t1x);
            const float ih = fminf(p2y, t2y) - fmaxf(p1y, t1y);
            const float inter = fmaxf(iw, 0.f) * fmaxf(ih, 0.f);
            const float pa = (p2x - p1x) * (p2y - p1y);
            const float ta = (t2x - t1x) * (t2y - t1y);
            const float uni = pa + ta - inter;
            box_s = 1.0f - inter / (uni + 1e-6f);
        }
    }
    __syncthreads();

    // ---------------- Phase 2: coalesced obj/cls sweep ----------------
    // Chunk slice: nanch*CH floats, base element divisible by 4 (nanch,CHUNK
    // multiples of 16; b*ATOT*CH multiple of 4) -> float4-aligned.
    float obj_s = 0.f, cls_s = 0.f;
    const float* base = pred + ((size_t)b * ATOT + (size_t)a0) * CH;
    const int ngroups = (nanch * CH) >> 2;   // exact: nanch % 4 == 0

    for (int g = threadIdx.x; g < ngroups; g += BLOCK) {
        const int le0 = g << 2;
        // la = le0 / 85 (magic), c0 = le0 % 85
        const unsigned la = __umulhi((unsigned)le0, 3233857729u) >> 6;
        const int c0 = le0 - (int)la * CH;
        const int m0 = smask[la];
        // group contributes iff it contains c==4 (obj) or class channels of a
        // pos anchor; wrapped elements (next anchor's c in [0,2]) never do.
        const bool need = (c0 >= 1 && c0 <= 4) || (m0 >= 0 && c0 >= 2);
        if (need) {
            const float4 x4 = *(const float4*)(base + le0);
            const float xs[4] = {x4.x, x4.y, x4.z, x4.w};
            #pragma unroll
            for (int j = 0; j < 4; ++j) {
                const int c = c0 + j;
                if (c == 4) {
                    obj_s += softplus_fast(xs[j]) - (m0 >= 0 ? xs[j] : 0.0f);
                } else if (c >= 5 && c < CH && m0 >= 0) {
                    cls_s += softplus_fast(xs[j]);
                    if (c - 5 == m0) cls_s -= xs[j];
                }
            }
        }
    }

    // ---------------- Combined block reduction ----------------
    float v0 = obj_s, v1 = cls_s, v2 = box_s, v3 = np_s;
    for (int off = 32; off > 0; off >>= 1) {
        v0 += __shfl_down(v0, off, 64);
        v1 += __shfl_down(v1, off, 64);
        v2 += __shfl_down(v2, off, 64);
        v3 += __shfl_down(v3, off, 64);
    }
    __shared__ float sred[BLOCK / 64][4];
    const int wave = threadIdx.x >> 6;
    const int lane = threadIdx.x & 63;
    if (lane == 0) {
        sred[wave][0] = v0; sred[wave][1] = v1;
        sred[wave][2] = v2; sred[wave][3] = v3;
    }
    __syncthreads();
    if (threadIdx.x == 0) {
        float t0 = 0.f, t1 = 0.f, t2 = 0.f, t3 = 0.f;
        #pragma unroll
        for (int w = 0; w < BLOCK / 64; ++w) {
            t0 += sred[w][0]; t1 += sred[w][1];
            t2 += sred[w][2]; t3 += sred[w][3];
        }
        atomicAdd(&acc[b * 4 + 0], t0);
        atomicAdd(&acc[b * 4 + 1], t1);
        atomicAdd(&acc[b * 4 + 2], t2);
        atomicAdd(&acc[b * 4 + 3], t3);
    }
}

// ---------------- Stage 2: per-image normalize + final reduce ---------------
__global__ void yolox_stage2(const float* __restrict__ acc,
                             float* __restrict__ out, int B) {
    float obj = 0.f, cls = 0.f, box = 0.f, np = 0.f;
    for (int b = threadIdx.x; b < B; b += 64) {
        const float os = acc[b * 4 + 0];
        const float cs = acc[b * 4 + 1];
        const float bs = acc[b * 4 + 2];
        const float ps = acc[b * 4 + 3];
        obj += os * (1.0f / (float)ATOT);
        const float denom = fmaxf(ps, 1.0f);
        cls += (ps > 0.f) ? cs / (denom * (float)NUM_CLASSES) : 0.f;
        box += (ps > 0.f) ? bs / denom : 0.f;
        np  += ps;
    }
    for (int off = 32; off > 0; off >>= 1) {
        obj += __shfl_down(obj, off, 64);
        cls += __shfl_down(cls, off, 64);
        box += __shfl_down(box, off, 64);
        np  += __shfl_down(np,  off, 64);
    }
    if (threadIdx.x == 0) {
        out[0] = 5.0f * box + obj + cls;  // total
        out[1] = box;
        out[2] = obj;
        out[3] = cls;
        out[4] = np;
    }
}

extern "C" void kernel_launch(void* const* d_in, const int* in_sizes, int n_in,
                              void* d_out, int out_size, void* d_ws, size_t ws_size,
                              hipStream_t stream) {
    const float* pred = (const float*)d_in[0];
    const float* tgt  = (const float*)d_in[1];
    const int*   isz  = (const int*)d_in[2];
    float* out = (float*)d_out;
    float* acc = (float*)d_ws;   // B*4 floats

    const int B = in_sizes[1] / (MT * 5);

    zero_acc_kernel<<<1, BLOCK, 0, stream>>>(acc, B * 4);

    dim3 grid(NBY, B);
    yolox_fused<<<grid, BLOCK, 0, stream>>>(pred, tgt, isz, acc);

    yolox_stage2<<<1, 64, 0, stream>>>(acc, out, B);
}

// Round 6
// 276.823 us; speedup vs baseline: 2.2440x; 1.0306x over previous
//
#include <hip/hip_runtime.h>
#include <math.h>

#define NUM_CLASSES 80
#define MT 50              // max targets per image
#define ATOT 8400          // 80*80 + 40*40 + 20*20
#define CH 85              // 5 + NUM_CLASSES
#define BLOCK 256
#define CHUNK 256          // anchors per block
#define NBY 33             // ceil(ATOT / CHUNK)

__device__ __forceinline__ float softplus_fast(float x) {
    // stable softplus via HW transcendentals: max(x,0) + log(1 + exp(-|x|))
    return fmaxf(x, 0.0f) + __logf(1.0f + __expf(-fabsf(x)));
}

// One block = (image b, 256-anchor chunk). Phase 1: ballot-compact targets,
// per-anchor match + box IoU + one-hot subtract; pos flags in LDS.
// Phase 2: coalesced float4 sweep of the chunk's contiguous pred slice.
__global__ __launch_bounds__(BLOCK) void yolox_fused(
        const float* __restrict__ pred,   // [B, ATOT, CH]
        const float* __restrict__ tgt,    // [B, MT, 5]
        const int*   __restrict__ isz,
        float* __restrict__ acc) {        // [B, NBY, 4] obj, cls, box, np
    const int b  = blockIdx.y;
    const int by = blockIdx.x;
    const int a0 = by * CHUNK;
    const int nanch = min(CHUNK, ATOT - a0);

    __shared__ float2 sxy[64];
    __shared__ float2 swh[64];
    __shared__ float  scls[64];
    __shared__ int    snv;
    __shared__ float  sposf[CHUNK];   // 1.0 if pos else 0.0

    // ---- wave-0 ballot compaction of valid targets (order-preserving) ----
    if (threadIdx.x < 64) {
        const int m = threadIdx.x;
        const float fsize = (float)(*isz);
        float c = -1.0f, x = 0.f, y = 0.f, w = 0.f, h = 0.f;
        if (m < MT) {
            const float* tb = tgt + (size_t)b * MT * 5 + (size_t)m * 5;
            c = tb[0];
            x = tb[1] * fsize; y = tb[2] * fsize;
            w = tb[3] * fsize; h = tb[4] * fsize;
        }
        const bool valid = (m < MT) && (c >= 0.0f);
        const unsigned long long ballot = __ballot(valid);
        const int slot = __popcll(ballot & ((1ull << threadIdx.x) - 1ull));
        if (valid) {
            sxy[slot]  = make_float2(x, y);
            swh[slot]  = make_float2(w, h);
            scls[slot] = c;
        }
        if (m == 0) snv = (int)__popcll(ballot);
    }
    sposf[threadIdx.x] = 0.0f;
    __syncthreads();
    const int nv = snv;

    // ---------------- Phase 1: match + box IoU + one-hot term ----------------
    float box_s = 0.f, np_s = 0.f, cls_s = 0.f, obj_s = 0.f;

    const int a = a0 + threadIdx.x;
    if (threadIdx.x < nanch) {
        // anchor geometry with compile-time divisors (magic-mul, no v_rcp div)
        float ax, ay;
        if (a < 6400)      { const int yy = a / 80;              const int xx = a - yy * 80;  ax = (float)(xx * 8  + 4);  ay = (float)(yy * 8  + 4); }
        else if (a < 8000) { const int i2 = a - 6400; const int yy = i2 / 40; const int xx = i2 - yy * 40; ax = (float)(xx * 16 + 8);  ay = (float)(yy * 16 + 8); }
        else               { const int i2 = a - 8000; const int yy = i2 / 20; const int xx = i2 - yy * 20; ax = (float)(xx * 32 + 16); ay = (float)(yy * 32 + 16); }

        float best = INFINITY;
        int bestm = 0;
        for (int m = 0; m < nv; ++m) {
            const float2 g = sxy[m];
            const float dx = g.x - ax, dy = g.y - ay;
            const float d2 = dx * dx + dy * dy;
            if (d2 < best) { best = d2; bestm = m; }
        }
        const bool pos = best < 4096.0f;  // 64^2

        if (pos) {
            sposf[threadIdx.x] = 1.0f;
            np_s = 1.0f;
            const float* p = pred + ((size_t)b * ATOT + (size_t)a) * CH;
            const int gcls = (int)scls[bestm];
            cls_s = -p[5 + gcls];          // one-hot subtract, once per anchor

            const float pcx = p[0], pcy = p[1];
            const float pw = __expf(p[2]), ph = __expf(p[3]);
            const float2 g  = sxy[bestm];
            const float2 wh = swh[bestm];
            const float p1x = pcx - pw * 0.5f, p2x = pcx + pw * 0.5f;
            const float p1y = pcy - ph * 0.5f, p2y = pcy + ph * 0.5f;
            const float t1x = g.x - wh.x * 0.5f, t2x = g.x + wh.x * 0.5f;
            const float t1y = g.y - wh.y * 0.5f, t2y = g.y + wh.y * 0.5f;
            const float iw = fminf(p2x, t2x) - fmaxf(p1x, t1x);
            const float ih = fminf(p2y, t2y) - fmaxf(p1y, t1y);
            const float inter = fmaxf(iw, 0.f) * fmaxf(ih, 0.f);
            const float pa = (p2x - p1x) * (p2y - p1y);
            const float ta = (t2x - t1x) * (t2y - t1y);
            const float uni = pa + ta - inter;
            box_s = 1.0f - inter / (uni + 1e-6f);
        }
    }
    __syncthreads();

    // ---------------- Phase 2: coalesced obj/cls sweep ----------------
    const float* base = pred + ((size_t)b * ATOT + (size_t)a0) * CH;
    const int ngroups = (nanch * CH) >> 2;   // exact: nanch % 4 == 0

    #pragma unroll 4
    for (int g = threadIdx.x; g < ngroups; g += BLOCK) {
        const int le0 = g << 2;
        // la = le0 / 85 (magic), c0 = le0 % 85
        const unsigned la = __umulhi((unsigned)le0, 3233857729u) >> 6;
        const int c0 = le0 - (int)la * CH;
        const float posf = sposf[la];
        const bool mpos = posf > 0.0f;
        // group contributes iff it contains c==4 (obj) or class channels of a
        // pos anchor; wrapped elements (next anchor's c in [0,2]) never do.
        const bool need = (c0 >= 1 && c0 <= 4) || (mpos && c0 >= 2);
        if (need) {
            const float4 x4 = *(const float4*)(base + le0);
            const float xs[4] = {x4.x, x4.y, x4.z, x4.w};
            #pragma unroll
            for (int j = 0; j < 4; ++j) {
                const int c = c0 + j;
                if (c == 4) {
                    obj_s += softplus_fast(xs[j]) - posf * xs[j];
                } else if (c >= 5 && c < CH && mpos) {
                    cls_s += softplus_fast(xs[j]);
                }
            }
        }
    }

    // ---------------- Combined block reduction ----------------
    float v0 = obj_s, v1 = cls_s, v2 = box_s, v3 = np_s;
    for (int off = 32; off > 0; off >>= 1) {
        v0 += __shfl_down(v0, off, 64);
        v1 += __shfl_down(v1, off, 64);
        v2 += __shfl_down(v2, off, 64);
        v3 += __shfl_down(v3, off, 64);
    }
    __shared__ float sred[BLOCK / 64][4];
    const int wave = threadIdx.x >> 6;
    const int lane = threadIdx.x & 63;
    if (lane == 0) {
        sred[wave][0] = v0; sred[wave][1] = v1;
        sred[wave][2] = v2; sred[wave][3] = v3;
    }
    __syncthreads();
    if (threadIdx.x == 0) {
        float t0 = 0.f, t1 = 0.f, t2 = 0.f, t3 = 0.f;
        #pragma unroll
        for (int w = 0; w < BLOCK / 64; ++w) {
            t0 += sred[w][0]; t1 += sred[w][1];
            t2 += sred[w][2]; t3 += sred[w][3];
        }
        float* slot = acc + ((size_t)b * NBY + by) * 4;
        slot[0] = t0; slot[1] = t1; slot[2] = t2; slot[3] = t3;
    }
}

// ---------------- Stage 2: per-image normalize + final reduce ---------------
__global__ __launch_bounds__(BLOCK) void yolox_stage2(
        const float* __restrict__ acc,    // [B, NBY, 4]
        float* __restrict__ out, int B) {
    float obj = 0.f, cls = 0.f, box = 0.f, np = 0.f;
    for (int bb = threadIdx.x; bb < B; bb += BLOCK) {
        float os = 0.f, cs = 0.f, bs = 0.f, ps = 0.f;
        const float* s = acc + (size_t)bb * NBY * 4;
        #pragma unroll
        for (int j = 0; j < NBY; ++j) {
            os += s[j * 4 + 0];
            cs += s[j * 4 + 1];
            bs += s[j * 4 + 2];
            ps += s[j * 4 + 3];
        }
        obj += os * (1.0f / (float)ATOT);
        const float denom = fmaxf(ps, 1.0f);
        cls += (ps > 0.f) ? cs / (denom * (float)NUM_CLASSES) : 0.f;
        box += (ps > 0.f) ? bs / denom : 0.f;
        np  += ps;
    }
    // block reduce 4 values
    float v0 = obj, v1 = cls, v2 = box, v3 = np;
    for (int off = 32; off > 0; off >>= 1) {
        v0 += __shfl_down(v0, off, 64);
        v1 += __shfl_down(v1, off, 64);
        v2 += __shfl_down(v2, off, 64);
        v3 += __shfl_down(v3, off, 64);
    }
    __shared__ float sred[BLOCK / 64][4];
    const int wave = threadIdx.x >> 6;
    const int lane = threadIdx.x & 63;
    if (lane == 0) {
        sred[wave][0] = v0; sred[wave][1] = v1;
        sred[wave][2] = v2; sred[wave][3] = v3;
    }
    __syncthreads();
    if (threadIdx.x == 0) {
        float t0 = 0.f, t1 = 0.f, t2 = 0.f, t3 = 0.f;
        #pragma unroll
        for (int w = 0; w < BLOCK / 64; ++w) {
            t0 += sred[w][0]; t1 += sred[w][1];
            t2 += sred[w][2]; t3 += sred[w][3];
        }
        out[0] = 5.0f * t2 + t0 + t1;  // total
        out[1] = t2;
        out[2] = t0;
        out[3] = t1;
        out[4] = t3;
    }
}

extern "C" void kernel_launch(void* const* d_in, const int* in_sizes, int n_in,
                              void* d_out, int out_size, void* d_ws, size_t ws_size,
                              hipStream_t stream) {
    const float* pred = (const float*)d_in[0];
    const float* tgt  = (const float*)d_in[1];
    const int*   isz  = (const int*)d_in[2];
    float* out = (float*)d_out;
    float* acc = (float*)d_ws;   // B*NBY*4 floats

    const int B = in_sizes[1] / (MT * 5);

    dim3 grid(NBY, B);
    yolox_fused<<<grid, BLOCK, 0, stream>>>(pred, tgt, isz, acc);
    yolox_stage2<<<1, BLOCK, 0, stream>>>(acc, out, B);
}

// Round 7
// 269.821 us; speedup vs baseline: 2.3023x; 1.0260x over previous
//
#include <hip/hip_runtime.h>
#include <math.h>

#define NUM_CLASSES 80
#define MT 50              // max targets per image
#define ATOT 8400          // 80*80 + 40*40 + 20*20
#define CH 85              // 5 + NUM_CLASSES
#define EPI (ATOT * CH)    // 714000 floats per image
#define EPG (EPI / 4)      // 178500 float4-groups per image
#define BLOCK 256
#define CHUNK 256          // anchors per match block
#define NBY 33             // ceil(ATOT / CHUNK)
#define NX 88              // bulk blocks per image
#define G 8                // groups per bulk thread (88*256*8 = 180224 >= EPG)

__device__ __forceinline__ float softplus_fast(float x) {
    // stable softplus via HW transcendentals: max(x,0) + log(1 + exp(-|x|))
    return fmaxf(x, 0.0f) + __logf(1.0f + __expf(-fabsf(x)));
}

// ---------------- Kernel 1: match + box IoU, gmask to global ----------------
__global__ __launch_bounds__(BLOCK) void yolox_match(
        const float* __restrict__ pred,   // [B, ATOT, CH]
        const float* __restrict__ tgt,    // [B, MT, 5]
        const int*   __restrict__ isz,
        int*   __restrict__ gmask,        // [B, ATOT]  pos ? gcls : -1
        float* __restrict__ accM) {       // [B, NBY, 2]  box, np
    const int b  = blockIdx.y;
    const int by = blockIdx.x;
    const int a0 = by * CHUNK;
    const int nanch = min(CHUNK, ATOT - a0);

    __shared__ float2 sxy[64];
    __shared__ float2 swh[64];
    __shared__ float  scls[64];
    __shared__ int    snv;

    // wave-0 ballot compaction of valid targets (order-preserving)
    if (threadIdx.x < 64) {
        const int m = threadIdx.x;
        const float fsize = (float)(*isz);
        float c = -1.0f, x = 0.f, y = 0.f, w = 0.f, h = 0.f;
        if (m < MT) {
            const float* tb = tgt + (size_t)b * MT * 5 + (size_t)m * 5;
            c = tb[0];
            x = tb[1] * fsize; y = tb[2] * fsize;
            w = tb[3] * fsize; h = tb[4] * fsize;
        }
        const bool valid = (m < MT) && (c >= 0.0f);
        const unsigned long long ballot = __ballot(valid);
        const int slot = __popcll(ballot & ((1ull << threadIdx.x) - 1ull));
        if (valid) {
            sxy[slot]  = make_float2(x, y);
            swh[slot]  = make_float2(w, h);
            scls[slot] = c;
        }
        if (m == 0) snv = (int)__popcll(ballot);
    }
    __syncthreads();
    const int nv = snv;

    float box_s = 0.f, np_s = 0.f;

    const int a = a0 + threadIdx.x;
    if (threadIdx.x < nanch) {
        // anchor geometry, compile-time divisors (magic-mul)
        float ax, ay;
        if (a < 6400)      { const int yy = a / 80;              const int xx = a - yy * 80;  ax = (float)(xx * 8  + 4);  ay = (float)(yy * 8  + 4); }
        else if (a < 8000) { const int i2 = a - 6400; const int yy = i2 / 40; const int xx = i2 - yy * 40; ax = (float)(xx * 16 + 8);  ay = (float)(yy * 16 + 8); }
        else               { const int i2 = a - 8000; const int yy = i2 / 20; const int xx = i2 - yy * 20; ax = (float)(xx * 32 + 16); ay = (float)(yy * 32 + 16); }

        float best = INFINITY;
        int bestm = 0;
        for (int m = 0; m < nv; ++m) {
            const float2 g = sxy[m];
            const float dx = g.x - ax, dy = g.y - ay;
            const float d2 = dx * dx + dy * dy;
            if (d2 < best) { best = d2; bestm = m; }
        }
        const bool pos = best < 4096.0f;  // 64^2

        gmask[(size_t)b * ATOT + a] = pos ? (int)scls[bestm] : -1;

        if (pos) {
            np_s = 1.0f;
            const float* p = pred + ((size_t)b * ATOT + (size_t)a) * CH;
            const float pcx = p[0], pcy = p[1];
            const float pw = __expf(p[2]), ph = __expf(p[3]);
            const float2 g  = sxy[bestm];
            const float2 wh = swh[bestm];
            const float p1x = pcx - pw * 0.5f, p2x = pcx + pw * 0.5f;
            const float p1y = pcy - ph * 0.5f, p2y = pcy + ph * 0.5f;
            const float t1x = g.x - wh.x * 0.5f, t2x = g.x + wh.x * 0.5f;
            const float t1y = g.y - wh.y * 0.5f, t2y = g.y + wh.y * 0.5f;
            const float iw = fminf(p2x, t2x) - fmaxf(p1x, t1x);
            const float ih = fminf(p2y, t2y) - fmaxf(p1y, t1y);
            const float inter = fmaxf(iw, 0.f) * fmaxf(ih, 0.f);
            const float pa = (p2x - p1x) * (p2y - p1y);
            const float ta = (t2x - t1x) * (t2y - t1y);
            const float uni = pa + ta - inter;
            box_s = 1.0f - inter / (uni + 1e-6f);
        }
    }

    float v2 = box_s, v3 = np_s;
    for (int off = 32; off > 0; off >>= 1) {
        v2 += __shfl_down(v2, off, 64);
        v3 += __shfl_down(v3, off, 64);
    }
    __shared__ float sred[BLOCK / 64][2];
    const int wave = threadIdx.x >> 6;
    const int lane = threadIdx.x & 63;
    if (lane == 0) { sred[wave][0] = v2; sred[wave][1] = v3; }
    __syncthreads();
    if (threadIdx.x == 0) {
        float t2 = 0.f, t3 = 0.f;
        #pragma unroll
        for (int w = 0; w < BLOCK / 64; ++w) { t2 += sred[w][0]; t3 += sred[w][1]; }
        float* slot = accM + ((size_t)b * NBY + by) * 2;
        slot[0] = t2; slot[1] = t3;
    }
}

// ---------------- Kernel 2: batched-ILP obj/cls sweep ----------------------
__global__ __launch_bounds__(BLOCK) void yolox_bulk(
        const float* __restrict__ pred,   // [B, ATOT, CH]
        const int*   __restrict__ gmask,  // [B, ATOT]
        float* __restrict__ accB) {       // [B, NX, 2]  obj, cls
    const int b   = blockIdx.y;
    const int tid = threadIdx.x;
    const int base_g = blockIdx.x * (BLOCK * G);

    const float* pbase = pred + (size_t)b * EPI;
    const int*   mbase = gmask + (size_t)b * ATOT;

    int  mk[G], c0k[G], lek[G];
    bool need[G];

    // batch 1: independent mask loads (all in flight together)
    #pragma unroll
    for (int k = 0; k < G; ++k) {
        const int g  = base_g + k * BLOCK + tid;
        const bool ok = g < EPG;
        const int le = g << 2;
        const unsigned la = __umulhi((unsigned)le, 3233857729u) >> 6;  // le/85
        lek[k] = le;
        c0k[k] = le - (int)la * CH;
        mk[k]  = ok ? mbase[la] : -1;
        need[k] = ok && ((c0k[k] >= 1 && c0k[k] <= 4) || (mk[k] >= 0 && c0k[k] >= 2));
    }

    // batch 2: independent predicated pred loads (all in flight together)
    float4 x[G];
    #pragma unroll
    for (int k = 0; k < G; ++k) {
        x[k] = need[k] ? *(const float4*)(pbase + lek[k])
                       : make_float4(0.f, 0.f, 0.f, 0.f);
    }

    // batch 3: compute
    float obj_s = 0.f, cls_s = 0.f;
    #pragma unroll
    for (int k = 0; k < G; ++k) {
        if (!need[k]) continue;
        const int c0 = c0k[k];
        const int m  = mk[k];
        const bool mpos = m >= 0;
        const float xs[4] = {x[k].x, x[k].y, x[k].z, x[k].w};
        #pragma unroll
        for (int j = 0; j < 4; ++j) {
            const int c = c0 + j;
            const float xv = xs[j];
            if (c == 4) {
                obj_s += softplus_fast(xv) - (mpos ? xv : 0.0f);
            } else if (c >= 5 && c < CH && mpos) {
                cls_s += softplus_fast(xv) - ((c - 5 == m) ? xv : 0.0f);
            }
        }
    }

    // block reduction
    float v0 = obj_s, v1 = cls_s;
    for (int off = 32; off > 0; off >>= 1) {
        v0 += __shfl_down(v0, off, 64);
        v1 += __shfl_down(v1, off, 64);
    }
    __shared__ float sred[BLOCK / 64][2];
    const int wave = threadIdx.x >> 6;
    const int lane = threadIdx.x & 63;
    if (lane == 0) { sred[wave][0] = v0; sred[wave][1] = v1; }
    __syncthreads();
    if (threadIdx.x == 0) {
        float t0 = 0.f, t1 = 0.f;
        #pragma unroll
        for (int w = 0; w < BLOCK / 64; ++w) { t0 += sred[w][0]; t1 += sred[w][1]; }
        float* slot = accB + ((size_t)b * NX + blockIdx.x) * 2;
        slot[0] = t0; slot[1] = t1;
    }
}

// ---------------- Stage 2: per-image normalize + final reduce ---------------
__global__ __launch_bounds__(BLOCK) void yolox_stage2(
        const float* __restrict__ accM,   // [B, NBY, 2] box, np
        const float* __restrict__ accB,   // [B, NX, 2]  obj, cls
        float* __restrict__ out, int B) {
    float obj = 0.f, cls = 0.f, box = 0.f, np = 0.f;
    for (int bb = threadIdx.x; bb < B; bb += BLOCK) {
        float bs = 0.f, ps = 0.f;
        const float* sM = accM + (size_t)bb * NBY * 2;
        #pragma unroll
        for (int j = 0; j < NBY; ++j) { bs += sM[j * 2 + 0]; ps += sM[j * 2 + 1]; }
        float os = 0.f, cs = 0.f;
        const float* sB = accB + (size_t)bb * NX * 2;
        #pragma unroll 8
        for (int j = 0; j < NX; ++j) { os += sB[j * 2 + 0]; cs += sB[j * 2 + 1]; }
        obj += os * (1.0f / (float)ATOT);
        const float denom = fmaxf(ps, 1.0f);
        cls += (ps > 0.f) ? cs / (denom * (float)NUM_CLASSES) : 0.f;
        box += (ps > 0.f) ? bs / denom : 0.f;
        np  += ps;
    }
    float v0 = obj, v1 = cls, v2 = box, v3 = np;
    for (int off = 32; off > 0; off >>= 1) {
        v0 += __shfl_down(v0, off, 64);
        v1 += __shfl_down(v1, off, 64);
        v2 += __shfl_down(v2, off, 64);
        v3 += __shfl_down(v3, off, 64);
    }
    __shared__ float sred[BLOCK / 64][4];
    const int wave = threadIdx.x >> 6;
    const int lane = threadIdx.x & 63;
    if (lane == 0) {
        sred[wave][0] = v0; sred[wave][1] = v1;
        sred[wave][2] = v2; sred[wave][3] = v3;
    }
    __syncthreads();
    if (threadIdx.x == 0) {
        float t0 = 0.f, t1 = 0.f, t2 = 0.f, t3 = 0.f;
        #pragma unroll
        for (int w = 0; w < BLOCK / 64; ++w) {
            t0 += sred[w][0]; t1 += sred[w][1];
            t2 += sred[w][2]; t3 += sred[w][3];
        }
        out[0] = 5.0f * t2 + t0 + t1;  // total
        out[1] = t2;
        out[2] = t0;
        out[3] = t1;
        out[4] = t3;
    }
}

extern "C" void kernel_launch(void* const* d_in, const int* in_sizes, int n_in,
                              void* d_out, int out_size, void* d_ws, size_t ws_size,
                              hipStream_t stream) {
    const float* pred = (const float*)d_in[0];
    const float* tgt  = (const float*)d_in[1];
    const int*   isz  = (const int*)d_in[2];
    float* out = (float*)d_out;

    const int B = in_sizes[1] / (MT * 5);

    // ws layout: gmask [B*ATOT] ints, accM [B*NBY*2] floats, accB [B*NX*2]
    int*   gmask = (int*)d_ws;
    float* accM  = (float*)((char*)d_ws + (size_t)B * ATOT * sizeof(int));
    float* accB  = accM + (size_t)B * NBY * 2;

    dim3 gridM(NBY, B);
    yolox_match<<<gridM, BLOCK, 0, stream>>>(pred, tgt, isz, gmask, accM);

    dim3 gridB(NX, B);
    yolox_bulk<<<gridB, BLOCK, 0, stream>>>(pred, gmask, accB);

    yolox_stage2<<<1, BLOCK, 0, stream>>>(accM, accB, out, B);
}